// Round 1
// baseline (329.741 us; speedup 1.0000x reference)
//
#include <hip/hip_runtime.h>
#include <cstdint>

#define WDIM 128
#define NPX  16384           // 128*128
#define SSTR 132             // LDS row stride (floats), 16B-aligned
#define PAD  16              // guard pads around x region for OOB-col reads
#define LDS_FLOATS (PAD + SSTR*WDIM + PAD + SSTR*WDIM)

__device__ __forceinline__ float wave_max(float v) {
#pragma unroll
  for (int m = 32; m >= 1; m >>= 1) v = fmaxf(v, __shfl_xor(v, m));
  return v;
}
__device__ __forceinline__ float wave_sum(float v) {
#pragma unroll
  for (int m = 32; m >= 1; m >>= 1) v += __shfl_xor(v, m);
  return v;
}

// ---------------- Kernel A: per-(b,c) conv -> matmul -> softmax -> *pool ----
// grid 2048 (= B*C), block 512. LDS: [pad][x->qT (132x128)][pad][k (132x128)]
template <int DIL>
__device__ __forceinline__ void dw_conv32(float* acc, const float* xq, int r,
                                          int cl, const float* w9) {
#pragma unroll
  for (int dr = 0; dr < 3; ++dr) {
    int rr = r + DIL * (dr - 1);
    if ((unsigned)rr < 128u) {
      const float* rp = &xq[rr * SSTR];
#pragma unroll
      for (int dc = 0; dc < 3; ++dc) {
        float wgt = w9[dr * 3 + dc];
        const int off = DIL * (dc - 1);
#pragma unroll
        for (int i = 0; i < 32; ++i) {
          int cc = cl + 4 * i + off;
          float v = rp[cc];  // safe: pads absorb cc in [-6,133]
          if (i <= 1 || i >= 30) v = ((unsigned)cc < 128u) ? v : 0.f;
          acc[i] = fmaf(wgt, v, acc[i]);
        }
      }
    }
  }
}

__global__ __launch_bounds__(512, 1)
void kA(const float* __restrict__ x, const float* __restrict__ wq,
        const float* __restrict__ bq, const float* __restrict__ wk,
        const float* __restrict__ bk, float* __restrict__ y) {
  extern __shared__ float lds[];
  float* xq = lds + PAD;                      // x plane, later overwritten by qT
  float* kk = lds + PAD + SSTR * WDIM + PAD;  // k plane

  const int bc = blockIdx.x;
  const int t = threadIdx.x;
  const float* __restrict__ xp = x + (size_t)bc * NPX;

  // phase 0: stage x into LDS (stride SSTR)
#pragma unroll
  for (int it = 0; it < 8; ++it) {
    int i = (t + it * 512) * 4;
    int r = i >> 7, c = i & 127;
    *(float4*)&xq[r * SSTR + c] = *(const float4*)&xp[i];
  }

  const int ch = bc & 255;
  float wq9[9], wk9[9];
#pragma unroll
  for (int i = 0; i < 9; ++i) { wq9[i] = wq[ch * 9 + i]; wk9[i] = wk[ch * 9 + i]; }
  const float bqv = bq[ch], bkv = bk[ch];
  __syncthreads();

  // phase 1: depthwise convs. thread -> row r = t>>2, pixels c = (t&3) + 4*i
  const int r = t >> 2, cl = t & 3;
  float aq[32], ak[32];
#pragma unroll
  for (int i = 0; i < 32; ++i) { aq[i] = bqv; ak[i] = bkv; }
  dw_conv32<3>(aq, xq, r, cl, wq9);
  dw_conv32<6>(ak, xq, r, cl, wk9);

  // write k plane (row-major) + pool partial
  float psum = 0.f;
#pragma unroll
  for (int i = 0; i < 32; ++i) { kk[r * SSTR + cl + 4 * i] = ak[i]; psum += ak[i]; }
  __syncthreads();  // all conv reads of x done
  // overwrite x region with qT (transposed: qT[col][row])
#pragma unroll
  for (int i = 0; i < 32; ++i) xq[(cl + 4 * i) * SSTR + r] = aq[i];
  __syncthreads();

  // phase 2: attn = q @ k. thread (ty,tx) -> rows i0..i0+3, cols j0..j0+7
  const int ty = t >> 4, tx = t & 15;
  const int i0 = ty * 4, j0 = tx * 8;
  float acc[4][8];
#pragma unroll
  for (int a = 0; a < 4; ++a)
#pragma unroll
    for (int b2 = 0; b2 < 8; ++b2) acc[a][b2] = 0.f;

#pragma unroll 2
  for (int m = 0; m < 128; ++m) {
    float4 qv = *(const float4*)&xq[m * SSTR + i0];
    float4 k0 = *(const float4*)&kk[m * SSTR + j0];
    float4 k1 = *(const float4*)&kk[m * SSTR + j0 + 4];
    float qf[4] = {qv.x, qv.y, qv.z, qv.w};
    float kf[8] = {k0.x, k0.y, k0.z, k0.w, k1.x, k1.y, k1.z, k1.w};
#pragma unroll
    for (int a = 0; a < 4; ++a)
#pragma unroll
      for (int b2 = 0; b2 < 8; ++b2) acc[a][b2] = fmaf(qf[a], kf[b2], acc[a][b2]);
  }

  // phase 3: plane softmax + pool scale
  float amax = -3.402823466e38f;
#pragma unroll
  for (int a = 0; a < 4; ++a)
#pragma unroll
    for (int b2 = 0; b2 < 8; ++b2) amax = fmaxf(amax, acc[a][b2]);
  amax = wave_max(amax);
  __syncthreads();  // matmul reads of kk complete -> reuse as scratch
  float* red = kk;
  const int wid = t >> 6, lane = t & 63;
  if (lane == 0) red[wid] = amax;
  __syncthreads();
  float bmax = red[0];
#pragma unroll
  for (int w2 = 1; w2 < 8; ++w2) bmax = fmaxf(bmax, red[w2]);

  float es = 0.f;
#pragma unroll
  for (int a = 0; a < 4; ++a)
#pragma unroll
    for (int b2 = 0; b2 < 8; ++b2) {
      float e = __expf(acc[a][b2] - bmax);
      acc[a][b2] = e;
      es += e;
    }
  es = wave_sum(es);
  float ps = wave_sum(psum);
  if (lane == 0) { red[8 + wid] = es; red[16 + wid] = ps; }
  __syncthreads();
  float tsum = 0.f, tpool = 0.f;
#pragma unroll
  for (int w2 = 0; w2 < 8; ++w2) { tsum += red[8 + w2]; tpool += red[16 + w2]; }
  const float scale = (tpool * (1.f / 16384.f)) / tsum;

  float* __restrict__ yp = y + (size_t)bc * NPX;
#pragma unroll
  for (int a = 0; a < 4; ++a) {
    float4 o0 = make_float4(acc[a][0] * scale, acc[a][1] * scale,
                            acc[a][2] * scale, acc[a][3] * scale);
    float4 o1 = make_float4(acc[a][4] * scale, acc[a][5] * scale,
                            acc[a][6] * scale, acc[a][7] * scale);
    *(float4*)&yp[(i0 + a) * WDIM + j0] = o0;
    *(float4*)&yp[(i0 + a) * WDIM + j0 + 4] = o1;
  }
}

// ---------------- Kernel B1: s = w_sq . y  (+ deterministic stats partials) --
// grid 512 (= B * 64 tiles), block 256, 1 pixel/thread
__global__ __launch_bounds__(256, 2)
void kB1(const float* __restrict__ y, const float* __restrict__ w_sq,
         float* __restrict__ sbuf, float* __restrict__ partials) {
  __shared__ float wl[32 * 256];
  __shared__ float wpart[4 * 64];
  const int t = threadIdx.x;
  for (int i = t; i < 8192; i += 256) wl[i] = w_sq[i];
  __syncthreads();
  const int b = blockIdx.x >> 6;
  const int tile = blockIdx.x & 63;
  const int p = tile * 256 + t;
  const float* __restrict__ yb = y + (size_t)b * 256 * NPX + p;

  float s[32];
#pragma unroll
  for (int d = 0; d < 32; ++d) s[d] = 0.f;

  for (int c0 = 0; c0 < 256; c0 += 8) {
    float yv[8];
#pragma unroll
    for (int cc = 0; cc < 8; ++cc) yv[cc] = yb[(size_t)(c0 + cc) * NPX];
#pragma unroll
    for (int d = 0; d < 32; ++d) {
      const float* wr = &wl[d * 256 + c0];
      float4 wa = *(const float4*)wr;
      float4 wb = *(const float4*)(wr + 4);
      s[d] = fmaf(wa.x, yv[0], s[d]);
      s[d] = fmaf(wa.y, yv[1], s[d]);
      s[d] = fmaf(wa.z, yv[2], s[d]);
      s[d] = fmaf(wa.w, yv[3], s[d]);
      s[d] = fmaf(wb.x, yv[4], s[d]);
      s[d] = fmaf(wb.y, yv[5], s[d]);
      s[d] = fmaf(wb.z, yv[6], s[d]);
      s[d] = fmaf(wb.w, yv[7], s[d]);
    }
  }

  float* __restrict__ sp = sbuf + (size_t)b * 32 * NPX + p;
#pragma unroll
  for (int d = 0; d < 32; ++d) sp[(size_t)d * NPX] = s[d];

  // per-wave reductions -> per-block partials (deterministic)
  const int wid = t >> 6, lane = t & 63;
#pragma unroll
  for (int d = 0; d < 32; ++d) {
    float sm = wave_sum(s[d]);
    float sq = wave_sum(s[d] * s[d]);
    if (lane == 0) { wpart[wid * 64 + d] = sm; wpart[wid * 64 + 32 + d] = sq; }
  }
  __syncthreads();
  if (t < 64) {
    float acc2 = wpart[t] + wpart[64 + t] + wpart[128 + t] + wpart[192 + t];
    partials[(size_t)blockIdx.x * 64 + t] = acc2;
  }
}

// ---------------- Kernel B2: InstanceNorm+ReLU, out = w_ex . s_hat + b_ex ----
// grid 512 (= B * 64 tiles), block 256, 1 pixel/thread
__global__ __launch_bounds__(256, 2)
void kB2(const float* __restrict__ sbuf, const float* __restrict__ partials,
         const float* __restrict__ w_ex, const float* __restrict__ b_ex,
         float* __restrict__ out) {
  __shared__ float wl[256 * 32];
  __shared__ float bl[256];
  __shared__ float mu[32], rs[32];
  const int t = threadIdx.x;
  for (int i = t; i < 8192; i += 256) wl[i] = w_ex[i];
  if (t < 256) bl[t] = b_ex[t];
  const int b = blockIdx.x >> 6;
  const int tile = blockIdx.x & 63;
  if (t < 32) {
    float sm = 0.f, sq = 0.f;
    for (int k2 = 0; k2 < 64; ++k2) {
      const float* pp = &partials[(size_t)(b * 64 + k2) * 64];
      sm += pp[t];
      sq += pp[32 + t];
    }
    float m = sm * (1.f / 16384.f);
    float v = sq * (1.f / 16384.f) - m * m;
    mu[t] = m;
    rs[t] = rsqrtf(v + 1e-5f);
  }
  __syncthreads();

  const int p = tile * 256 + t;
  const float* __restrict__ sp = sbuf + (size_t)b * 32 * NPX + p;
  float sh[32];
#pragma unroll
  for (int d = 0; d < 32; ++d) {
    float v = (sp[(size_t)d * NPX] - mu[d]) * rs[d];
    sh[d] = fmaxf(v, 0.f);
  }
  float* __restrict__ op = out + (size_t)b * 256 * NPX + p;
  for (int c = 0; c < 256; ++c) {
    float a = bl[c];
    const float* wr = &wl[c * 32];
#pragma unroll
    for (int d0 = 0; d0 < 32; d0 += 4) {
      float4 w4 = *(const float4*)&wr[d0];
      a = fmaf(w4.x, sh[d0], a);
      a = fmaf(w4.y, sh[d0 + 1], a);
      a = fmaf(w4.z, sh[d0 + 2], a);
      a = fmaf(w4.w, sh[d0 + 3], a);
    }
    op[(size_t)c * NPX] = a;
  }
}

extern "C" void kernel_launch(void* const* d_in, const int* in_sizes, int n_in,
                              void* d_out, int out_size, void* d_ws, size_t ws_size,
                              hipStream_t stream) {
  (void)in_sizes; (void)n_in; (void)out_size; (void)ws_size;
  const float* x    = (const float*)d_in[0];
  const float* wq   = (const float*)d_in[1];
  const float* bq   = (const float*)d_in[2];
  const float* wk   = (const float*)d_in[3];
  const float* bk   = (const float*)d_in[4];
  const float* w_sq = (const float*)d_in[5];
  // d_in[6] = b_sq: unused — a per-channel bias before InstanceNorm cancels
  const float* w_ex = (const float*)d_in[7];
  const float* b_ex = (const float*)d_in[8];
  float* out = (float*)d_out;

  float* sbuf = (float*)d_ws;                       // 8*32*16384 floats (16.8 MB)
  float* partials = sbuf + (size_t)8 * 32 * NPX;    // 512*64 floats

  const size_t ldsA = LDS_FLOATS * sizeof(float);   // ~135 KB
  hipFuncSetAttribute((const void*)kA, hipFuncAttributeMaxDynamicSharedMemorySize,
                      (int)ldsA);

  // y is staged in d_out (fully consumed by kB1 before kB2 overwrites it)
  kA<<<2048, 512, ldsA, stream>>>(x, wq, bq, wk, bk, out);
  kB1<<<512, 256, 0, stream>>>(out, w_sq, sbuf, partials);
  kB2<<<512, 256, 0, stream>>>(sbuf, partials, w_ex, b_ex, out);
}

// Round 2
// 254.231 us; speedup vs baseline: 1.2970x; 1.2970x over previous
//
#include <hip/hip_runtime.h>
#include <cstdint>

#define WDIM 128
#define NPX  16384           // 128*128
#define XSTR 132             // fp32 x LDS row stride (floats)
#define QSTR 136             // bf16 q/kT LDS row stride (shorts), 16B-aligned rows
#define XPAD 16              // guard pad before x region for OOB-col reads
// LDS layout (bytes): [0, 34816) qb | [34816, 69632) kT | x fp32 overlays [0,67776)
// scratch reds at 69632. Total 69888 B -> 2 blocks/CU.
#define LDS_A_BYTES 69888

typedef __attribute__((ext_vector_type(8))) short short8;
typedef __attribute__((ext_vector_type(4))) float f32x4;

__device__ __forceinline__ float wave_max(float v) {
#pragma unroll
  for (int m = 32; m >= 1; m >>= 1) v = fmaxf(v, __shfl_xor(v, m));
  return v;
}
__device__ __forceinline__ float wave_sum(float v) {
#pragma unroll
  for (int m = 32; m >= 1; m >>= 1) v += __shfl_xor(v, m);
  return v;
}
__device__ __forceinline__ unsigned short f2bf(float f) {
  uint32_t u = __float_as_uint(f);
  return (unsigned short)((u + 0x7fff + ((u >> 16) & 1)) >> 16);
}
__device__ __forceinline__ float bf2f(unsigned short h) {
  return __uint_as_float(((uint32_t)h) << 16);
}

// depthwise 3x3 dilated conv over x staged in LDS (stride XSTR, front pad)
template <int DIL>
__device__ __forceinline__ void dw_conv32(float* acc, const float* xq, int r,
                                          int cl, const float* w9) {
#pragma unroll
  for (int dr = 0; dr < 3; ++dr) {
    int rr = r + DIL * (dr - 1);
    if ((unsigned)rr < 128u) {
      const float* rp = &xq[rr * XSTR];
#pragma unroll
      for (int dc = 0; dc < 3; ++dc) {
        float wgt = w9[dr * 3 + dc];
        const int off = DIL * (dc - 1);
#pragma unroll
        for (int i = 0; i < 32; ++i) {
          int cc = cl + 4 * i + off;
          float v = rp[cc];  // pad absorbs cc in [-6,133]
          if (i <= 1 || i >= 30) v = ((unsigned)cc < 128u) ? v : 0.f;
          acc[i] = fmaf(wgt, v, acc[i]);
        }
      }
    }
  }
}

// ---------------- Kernel A: conv -> bf16 MFMA matmul -> softmax -> *pool ----
// grid 2048 (= B*C), block 512 (8 waves)
__global__ __launch_bounds__(512, 4)
void kA(const float* __restrict__ x, const float* __restrict__ wq,
        const float* __restrict__ bq, const float* __restrict__ wk,
        const float* __restrict__ bk, unsigned short* __restrict__ y) {
  extern __shared__ char smem[];
  float* xq = (float*)smem + XPAD;                 // x fp32, stride XSTR
  unsigned short* qb = (unsigned short*)smem;      // q bf16 row-major [128][QSTR]
  unsigned short* kt = (unsigned short*)(smem + 34816);  // kT bf16 [128][QSTR]
  float* red = (float*)(smem + 69632);             // cross-wave scratch

  const int bc = blockIdx.x;
  const int t = threadIdx.x;
  const float* __restrict__ xp = x + (size_t)bc * NPX;

  // phase 0: stage x into LDS
#pragma unroll
  for (int it = 0; it < 8; ++it) {
    int i = (t + it * 512) * 4;
    int r = i >> 7, c = i & 127;
    *(float4*)&xq[r * XSTR + c] = *(const float4*)&xp[i];
  }

  const int ch = bc & 255;
  float wq9[9], wk9[9];
#pragma unroll
  for (int i = 0; i < 9; ++i) { wq9[i] = wq[ch * 9 + i]; wk9[i] = wk[ch * 9 + i]; }
  const float bqv = bq[ch], bkv = bk[ch];
  __syncthreads();

  // phase 1: convs. thread -> row r = t>>2, pixels c = (t&3) + 4*i
  const int r = t >> 2, cl = t & 3;
  float aq[32], ak[32];
#pragma unroll
  for (int i = 0; i < 32; ++i) { aq[i] = bqv; ak[i] = bkv; }
  dw_conv32<3>(aq, xq, r, cl, wq9);
  dw_conv32<6>(ak, xq, r, cl, wk9);

  float psum = 0.f;
#pragma unroll
  for (int i = 0; i < 32; ++i) psum += ak[i];

  __syncthreads();  // all conv reads of x complete

  // phase 2: write bf16 fragments (overlaying x region)
#pragma unroll
  for (int i = 0; i < 32; ++i) {
    int c = cl + 4 * i;
    qb[r * QSTR + c] = f2bf(aq[i]);   // q row-major
    kt[c * QSTR + r] = f2bf(ak[i]);   // k transposed
  }
  __syncthreads();

  // phase 3: attn = q @ k via MFMA 16x16x32 bf16.
  // wave w: rows wr*64..+63 (4 M-tiles), cols wc*32..+31 (2 N-tiles)
  const int w = t >> 6, lane = t & 63;
  const int wr = w >> 2, wc = w & 3;
  const int r16 = lane & 15, kg = lane >> 4;
  f32x4 acc[4][2];
#pragma unroll
  for (int mi = 0; mi < 4; ++mi)
#pragma unroll
    for (int ni = 0; ni < 2; ++ni) acc[mi][ni] = (f32x4){0.f, 0.f, 0.f, 0.f};

#pragma unroll
  for (int kk = 0; kk < 4; ++kk) {
    const int kb = kk * 32 + kg * 8;
    short8 a0 = *(const short8*)&qb[(wr * 64 + 0 * 16 + r16) * QSTR + kb];
    short8 a1 = *(const short8*)&qb[(wr * 64 + 1 * 16 + r16) * QSTR + kb];
    short8 a2 = *(const short8*)&qb[(wr * 64 + 2 * 16 + r16) * QSTR + kb];
    short8 a3 = *(const short8*)&qb[(wr * 64 + 3 * 16 + r16) * QSTR + kb];
    short8 b0 = *(const short8*)&kt[(wc * 32 + 0 + r16) * QSTR + kb];
    short8 b1 = *(const short8*)&kt[(wc * 32 + 16 + r16) * QSTR + kb];
    acc[0][0] = __builtin_amdgcn_mfma_f32_16x16x32_bf16(a0, b0, acc[0][0], 0, 0, 0);
    acc[0][1] = __builtin_amdgcn_mfma_f32_16x16x32_bf16(a0, b1, acc[0][1], 0, 0, 0);
    acc[1][0] = __builtin_amdgcn_mfma_f32_16x16x32_bf16(a1, b0, acc[1][0], 0, 0, 0);
    acc[1][1] = __builtin_amdgcn_mfma_f32_16x16x32_bf16(a1, b1, acc[1][1], 0, 0, 0);
    acc[2][0] = __builtin_amdgcn_mfma_f32_16x16x32_bf16(a2, b0, acc[2][0], 0, 0, 0);
    acc[2][1] = __builtin_amdgcn_mfma_f32_16x16x32_bf16(a2, b1, acc[2][1], 0, 0, 0);
    acc[3][0] = __builtin_amdgcn_mfma_f32_16x16x32_bf16(a3, b0, acc[3][0], 0, 0, 0);
    acc[3][1] = __builtin_amdgcn_mfma_f32_16x16x32_bf16(a3, b1, acc[3][1], 0, 0, 0);
  }

  // phase 4: plane softmax + pool scale
  float amax = -3.402823466e38f;
#pragma unroll
  for (int mi = 0; mi < 4; ++mi)
#pragma unroll
    for (int ni = 0; ni < 2; ++ni)
#pragma unroll
      for (int j = 0; j < 4; ++j) amax = fmaxf(amax, acc[mi][ni][j]);
  amax = wave_max(amax);
  if (lane == 0) red[w] = amax;
  __syncthreads();
  float bmax = red[0];
#pragma unroll
  for (int w2 = 1; w2 < 8; ++w2) bmax = fmaxf(bmax, red[w2]);

  float es = 0.f;
#pragma unroll
  for (int mi = 0; mi < 4; ++mi)
#pragma unroll
    for (int ni = 0; ni < 2; ++ni)
#pragma unroll
      for (int j = 0; j < 4; ++j) {
        float e = __expf(acc[mi][ni][j] - bmax);
        acc[mi][ni][j] = e;
        es += e;
      }
  es = wave_sum(es);
  float ps = wave_sum(psum);
  if (lane == 0) { red[8 + w] = es; red[16 + w] = ps; }
  __syncthreads();
  float tsum = 0.f, tpool = 0.f;
#pragma unroll
  for (int w2 = 0; w2 < 8; ++w2) { tsum += red[8 + w2]; tpool += red[16 + w2]; }
  const float scale = (tpool * (1.f / 16384.f)) / tsum;

  // phase 5: y (bf16) write. D layout: col = lane&15, row = kg*4 + j
  unsigned short* __restrict__ yp = y + (size_t)bc * NPX;
#pragma unroll
  for (int mi = 0; mi < 4; ++mi)
#pragma unroll
    for (int ni = 0; ni < 2; ++ni) {
      const int col = wc * 32 + ni * 16 + r16;
#pragma unroll
      for (int j = 0; j < 4; ++j) {
        const int row = wr * 64 + mi * 16 + kg * 4 + j;
        yp[row * WDIM + col] = f2bf(acc[mi][ni][j] * scale);
      }
    }
}

// ---------------- Kernel B1: s = w_sq . y  (+ deterministic stats partials) --
__global__ __launch_bounds__(256, 2)
void kB1(const unsigned short* __restrict__ y, const float* __restrict__ w_sq,
         float* __restrict__ sbuf, float* __restrict__ partials) {
  __shared__ float wl[32 * 256];
  __shared__ float wpart[4 * 64];
  const int t = threadIdx.x;
  for (int i = t; i < 8192; i += 256) wl[i] = w_sq[i];
  __syncthreads();
  const int b = blockIdx.x >> 6;
  const int tile = blockIdx.x & 63;
  const int p = tile * 256 + t;
  const unsigned short* __restrict__ yb = y + (size_t)b * 256 * NPX + p;

  float s[32];
#pragma unroll
  for (int d = 0; d < 32; ++d) s[d] = 0.f;

  for (int c0 = 0; c0 < 256; c0 += 8) {
    float yv[8];
#pragma unroll
    for (int cc = 0; cc < 8; ++cc) yv[cc] = bf2f(yb[(size_t)(c0 + cc) * NPX]);
#pragma unroll
    for (int d = 0; d < 32; ++d) {
      const float* wr = &wl[d * 256 + c0];
      float4 wa = *(const float4*)wr;
      float4 wb = *(const float4*)(wr + 4);
      s[d] = fmaf(wa.x, yv[0], s[d]);
      s[d] = fmaf(wa.y, yv[1], s[d]);
      s[d] = fmaf(wa.z, yv[2], s[d]);
      s[d] = fmaf(wa.w, yv[3], s[d]);
      s[d] = fmaf(wb.x, yv[4], s[d]);
      s[d] = fmaf(wb.y, yv[5], s[d]);
      s[d] = fmaf(wb.z, yv[6], s[d]);
      s[d] = fmaf(wb.w, yv[7], s[d]);
    }
  }

  float* __restrict__ sp = sbuf + (size_t)b * 32 * NPX + p;
#pragma unroll
  for (int d = 0; d < 32; ++d) sp[(size_t)d * NPX] = s[d];

  const int wid = t >> 6, lane = t & 63;
#pragma unroll
  for (int d = 0; d < 32; ++d) {
    float sm = wave_sum(s[d]);
    float sq = wave_sum(s[d] * s[d]);
    if (lane == 0) { wpart[wid * 64 + d] = sm; wpart[wid * 64 + 32 + d] = sq; }
  }
  __syncthreads();
  if (t < 64) {
    float acc2 = wpart[t] + wpart[64 + t] + wpart[128 + t] + wpart[192 + t];
    partials[(size_t)blockIdx.x * 64 + t] = acc2;
  }
}

// ---------------- Kernel B2: InstanceNorm+ReLU, out = w_ex . s_hat + b_ex ----
__global__ __launch_bounds__(256, 2)
void kB2(const float* __restrict__ sbuf, const float* __restrict__ partials,
         const float* __restrict__ w_ex, const float* __restrict__ b_ex,
         float* __restrict__ out) {
  __shared__ float wl[256 * 32];
  __shared__ float bl[256];
  __shared__ float mu[32], rs[32];
  const int t = threadIdx.x;
  for (int i = t; i < 8192; i += 256) wl[i] = w_ex[i];
  if (t < 256) bl[t] = b_ex[t];
  const int b = blockIdx.x >> 6;
  const int tile = blockIdx.x & 63;
  if (t < 32) {
    float sm = 0.f, sq = 0.f;
    for (int k2 = 0; k2 < 64; ++k2) {
      const float* pp = &partials[(size_t)(b * 64 + k2) * 64];
      sm += pp[t];
      sq += pp[32 + t];
    }
    float m = sm * (1.f / 16384.f);
    float v = sq * (1.f / 16384.f) - m * m;
    mu[t] = m;
    rs[t] = rsqrtf(v + 1e-5f);
  }
  __syncthreads();

  const int p = tile * 256 + t;
  const float* __restrict__ sp = sbuf + (size_t)b * 32 * NPX + p;
  float sh[32];
#pragma unroll
  for (int d = 0; d < 32; ++d) {
    float v = (sp[(size_t)d * NPX] - mu[d]) * rs[d];
    sh[d] = fmaxf(v, 0.f);
  }
  float* __restrict__ op = out + (size_t)b * 256 * NPX + p;
  for (int c = 0; c < 256; ++c) {
    float a = bl[c];
    const float* wr = &wl[c * 32];
#pragma unroll
    for (int d0 = 0; d0 < 32; d0 += 4) {
      float4 w4 = *(const float4*)&wr[d0];
      a = fmaf(w4.x, sh[d0], a);
      a = fmaf(w4.y, sh[d0 + 1], a);
      a = fmaf(w4.z, sh[d0 + 2], a);
      a = fmaf(w4.w, sh[d0 + 3], a);
    }
    op[(size_t)c * NPX] = a;
  }
}

extern "C" void kernel_launch(void* const* d_in, const int* in_sizes, int n_in,
                              void* d_out, int out_size, void* d_ws, size_t ws_size,
                              hipStream_t stream) {
  (void)in_sizes; (void)n_in; (void)out_size; (void)ws_size;
  const float* x    = (const float*)d_in[0];
  const float* wq   = (const float*)d_in[1];
  const float* bq   = (const float*)d_in[2];
  const float* wk   = (const float*)d_in[3];
  const float* bk   = (const float*)d_in[4];
  const float* w_sq = (const float*)d_in[5];
  // d_in[6] = b_sq: unused — per-channel bias before InstanceNorm cancels
  const float* w_ex = (const float*)d_in[7];
  const float* b_ex = (const float*)d_in[8];
  float* out = (float*)d_out;

  float* sbuf = (float*)d_ws;                       // 8*32*16384 floats (16.8 MB)
  float* partials = sbuf + (size_t)8 * 32 * NPX;    // 512*64 floats

  // y (bf16) staged in d_out; fully consumed by kB1 before kB2 overwrites
  unsigned short* ybf = (unsigned short*)d_out;

  hipFuncSetAttribute((const void*)kA, hipFuncAttributeMaxDynamicSharedMemorySize,
                      LDS_A_BYTES);

  kA<<<2048, 512, LDS_A_BYTES, stream>>>(x, wq, bq, wk, bk, ybf);
  kB1<<<512, 256, 0, stream>>>(ybf, w_sq, sbuf, partials);
  kB2<<<512, 256, 0, stream>>>(sbuf, partials, w_ex, b_ex, out);
}

// Round 3
// 131.569 us; speedup vs baseline: 2.5062x; 1.9323x over previous
//
#include <hip/hip_runtime.h>
#include <cstdint>

#define WDIM 128
#define NPX  16384           // 128*128
#define XSTR 132             // fp32 x LDS row stride (floats)
#define QSTR 136             // bf16 q/kT LDS row stride (shorts), 16B-aligned rows
#define XPAD 16              // guard pad before x region for OOB-col reads
#define LDS_A_BYTES 69888

typedef __attribute__((ext_vector_type(8))) short short8;
typedef __attribute__((ext_vector_type(4))) float f32x4;

__device__ __forceinline__ float wave_max(float v) {
#pragma unroll
  for (int m = 32; m >= 1; m >>= 1) v = fmaxf(v, __shfl_xor(v, m));
  return v;
}
__device__ __forceinline__ float wave_sum(float v) {
#pragma unroll
  for (int m = 32; m >= 1; m >>= 1) v += __shfl_xor(v, m);
  return v;
}
__device__ __forceinline__ unsigned short f2bf(float f) {
  uint32_t u = __float_as_uint(f);
  return (unsigned short)((u + 0x7fff + ((u >> 16) & 1)) >> 16);
}
__device__ __forceinline__ float bf2f(unsigned short h) {
  return __uint_as_float(((uint32_t)h) << 16);
}

// depthwise 3x3 dilated conv over x staged in LDS (stride XSTR, front pad)
template <int DIL>
__device__ __forceinline__ void dw_conv32(float* acc, const float* xq, int r,
                                          int cl, const float* w9) {
#pragma unroll
  for (int dr = 0; dr < 3; ++dr) {
    int rr = r + DIL * (dr - 1);
    if ((unsigned)rr < 128u) {
      const float* rp = &xq[rr * XSTR];
#pragma unroll
      for (int dc = 0; dc < 3; ++dc) {
        float wgt = w9[dr * 3 + dc];
        const int off = DIL * (dc - 1);
#pragma unroll
        for (int i = 0; i < 32; ++i) {
          int cc = cl + 4 * i + off;
          float v = rp[cc];  // pad absorbs cc in [-6,133]
          if (i <= 1 || i >= 30) v = ((unsigned)cc < 128u) ? v : 0.f;
          acc[i] = fmaf(wgt, v, acc[i]);
        }
      }
    }
  }
}

// ---------------- Kernel A: conv -> bf16 MFMA matmul -> softmax -> *pool ----
__global__ __launch_bounds__(512, 4)
void kA(const float* __restrict__ x, const float* __restrict__ wq,
        const float* __restrict__ bq, const float* __restrict__ wk,
        const float* __restrict__ bk, unsigned short* __restrict__ y) {
  extern __shared__ char smem[];
  float* xq = (float*)smem + XPAD;
  unsigned short* qb = (unsigned short*)smem;
  unsigned short* kt = (unsigned short*)(smem + 34816);
  float* red = (float*)(smem + 69632);

  const int bc = blockIdx.x;
  const int t = threadIdx.x;
  const float* __restrict__ xp = x + (size_t)bc * NPX;

#pragma unroll
  for (int it = 0; it < 8; ++it) {
    int i = (t + it * 512) * 4;
    int r = i >> 7, c = i & 127;
    *(float4*)&xq[r * XSTR + c] = *(const float4*)&xp[i];
  }

  const int ch = bc & 255;
  float wq9[9], wk9[9];
#pragma unroll
  for (int i = 0; i < 9; ++i) { wq9[i] = wq[ch * 9 + i]; wk9[i] = wk[ch * 9 + i]; }
  const float bqv = bq[ch], bkv = bk[ch];
  __syncthreads();

  const int r = t >> 2, cl = t & 3;
  float aq[32], ak[32];
#pragma unroll
  for (int i = 0; i < 32; ++i) { aq[i] = bqv; ak[i] = bkv; }
  dw_conv32<3>(aq, xq, r, cl, wq9);
  dw_conv32<6>(ak, xq, r, cl, wk9);

  float psum = 0.f;
#pragma unroll
  for (int i = 0; i < 32; ++i) psum += ak[i];

  __syncthreads();

#pragma unroll
  for (int i = 0; i < 32; ++i) {
    int c = cl + 4 * i;
    qb[r * QSTR + c] = f2bf(aq[i]);
    kt[c * QSTR + r] = f2bf(ak[i]);
  }
  __syncthreads();

  const int w = t >> 6, lane = t & 63;
  const int wr = w >> 2, wc = w & 3;
  const int r16 = lane & 15, kg = lane >> 4;
  f32x4 acc[4][2];
#pragma unroll
  for (int mi = 0; mi < 4; ++mi)
#pragma unroll
    for (int ni = 0; ni < 2; ++ni) acc[mi][ni] = (f32x4){0.f, 0.f, 0.f, 0.f};

#pragma unroll
  for (int kk = 0; kk < 4; ++kk) {
    const int kb = kk * 32 + kg * 8;
    short8 a0 = *(const short8*)&qb[(wr * 64 + 0 * 16 + r16) * QSTR + kb];
    short8 a1 = *(const short8*)&qb[(wr * 64 + 1 * 16 + r16) * QSTR + kb];
    short8 a2 = *(const short8*)&qb[(wr * 64 + 2 * 16 + r16) * QSTR + kb];
    short8 a3 = *(const short8*)&qb[(wr * 64 + 3 * 16 + r16) * QSTR + kb];
    short8 b0 = *(const short8*)&kt[(wc * 32 + 0 + r16) * QSTR + kb];
    short8 b1 = *(const short8*)&kt[(wc * 32 + 16 + r16) * QSTR + kb];
    acc[0][0] = __builtin_amdgcn_mfma_f32_16x16x32_bf16(a0, b0, acc[0][0], 0, 0, 0);
    acc[0][1] = __builtin_amdgcn_mfma_f32_16x16x32_bf16(a0, b1, acc[0][1], 0, 0, 0);
    acc[1][0] = __builtin_amdgcn_mfma_f32_16x16x32_bf16(a1, b0, acc[1][0], 0, 0, 0);
    acc[1][1] = __builtin_amdgcn_mfma_f32_16x16x32_bf16(a1, b1, acc[1][1], 0, 0, 0);
    acc[2][0] = __builtin_amdgcn_mfma_f32_16x16x32_bf16(a2, b0, acc[2][0], 0, 0, 0);
    acc[2][1] = __builtin_amdgcn_mfma_f32_16x16x32_bf16(a2, b1, acc[2][1], 0, 0, 0);
    acc[3][0] = __builtin_amdgcn_mfma_f32_16x16x32_bf16(a3, b0, acc[3][0], 0, 0, 0);
    acc[3][1] = __builtin_amdgcn_mfma_f32_16x16x32_bf16(a3, b1, acc[3][1], 0, 0, 0);
  }

  float amax = -3.402823466e38f;
#pragma unroll
  for (int mi = 0; mi < 4; ++mi)
#pragma unroll
    for (int ni = 0; ni < 2; ++ni)
#pragma unroll
      for (int j = 0; j < 4; ++j) amax = fmaxf(amax, acc[mi][ni][j]);
  amax = wave_max(amax);
  if (lane == 0) red[w] = amax;
  __syncthreads();
  float bmax = red[0];
#pragma unroll
  for (int w2 = 1; w2 < 8; ++w2) bmax = fmaxf(bmax, red[w2]);

  float es = 0.f;
#pragma unroll
  for (int mi = 0; mi < 4; ++mi)
#pragma unroll
    for (int ni = 0; ni < 2; ++ni)
#pragma unroll
      for (int j = 0; j < 4; ++j) {
        float e = __expf(acc[mi][ni][j] - bmax);
        acc[mi][ni][j] = e;
        es += e;
      }
  es = wave_sum(es);
  float ps = wave_sum(psum);
  if (lane == 0) { red[8 + w] = es; red[16 + w] = ps; }
  __syncthreads();
  float tsum = 0.f, tpool = 0.f;
#pragma unroll
  for (int w2 = 0; w2 < 8; ++w2) { tsum += red[8 + w2]; tpool += red[16 + w2]; }
  const float scale = (tpool * (1.f / 16384.f)) / tsum;

  unsigned short* __restrict__ yp = y + (size_t)bc * NPX;
#pragma unroll
  for (int mi = 0; mi < 4; ++mi)
#pragma unroll
    for (int ni = 0; ni < 2; ++ni) {
      const int col = wc * 32 + ni * 16 + r16;
#pragma unroll
      for (int j = 0; j < 4; ++j) {
        const int row = wr * 64 + mi * 16 + kg * 4 + j;
        yp[row * WDIM + col] = f2bf(acc[mi][ni][j] * scale);
      }
    }
}

// ---------------- Kernel S: s = w_sq . y via MFMA + stats + sT (bf16) -------
// grid 512 (b = blk>>6, chunk = blk&63 -> 256 px), block 256 (4 waves)
__global__ __launch_bounds__(256, 2)
void kS(const unsigned short* __restrict__ y, const float* __restrict__ w_sq,
        unsigned short* __restrict__ sT, float* __restrict__ partials) {
  __shared__ unsigned short yT[64][264];   // [px][c], 528B rows (16B-aligned)
  __shared__ float red[256];
  const int t = threadIdx.x;
  const int w = t >> 6, lane = t & 63;
  const int r16 = lane & 15, kg = lane >> 4;
  const int b = blockIdx.x >> 6;
  const int chunk = blockIdx.x & 63;
  const unsigned short* __restrict__ yb = y + (size_t)b * 256 * NPX;

  // A-frags: w_sq (fp32 [32][256]) -> bf16, kept in registers
  short8 aw[2][8];
#pragma unroll
  for (int mt = 0; mt < 2; ++mt)
#pragma unroll
    for (int ks = 0; ks < 8; ++ks) {
      const float* p = &w_sq[(mt * 16 + r16) * 256 + ks * 32 + kg * 8];
      float4 f0 = *(const float4*)p;
      float4 f1 = *(const float4*)(p + 4);
      short8 a;
      a[0] = f2bf(f0.x); a[1] = f2bf(f0.y); a[2] = f2bf(f0.z); a[3] = f2bf(f0.w);
      a[4] = f2bf(f1.x); a[5] = f2bf(f1.y); a[6] = f2bf(f1.z); a[7] = f2bf(f1.w);
      aw[mt][ks] = a;
    }

  float ssum[8], ssq[8];
#pragma unroll
  for (int i = 0; i < 8; ++i) { ssum[i] = 0.f; ssq[i] = 0.f; }

  for (int st = 0; st < 4; ++st) {
    const int p0 = chunk * 256 + st * 64;
    // transpose-stage y[256c][64px] -> yT[64px][256c]
#pragma unroll
    for (int it = 0; it < 8; ++it) {
      const int tid = it * 4 + w;
      const int cg = tid & 3, pg = tid >> 2;
      const int c = cg * 64 + lane;
      short8 v = *(const short8*)&yb[(size_t)c * NPX + p0 + pg * 8];
#pragma unroll
      for (int j = 0; j < 8; ++j) yT[pg * 8 + j][c] = (unsigned short)v[j];
    }
    __syncthreads();

    f32x4 acc[2][4];
#pragma unroll
    for (int mi = 0; mi < 2; ++mi)
#pragma unroll
      for (int ni = 0; ni < 4; ++ni) acc[mi][ni] = (f32x4){0.f, 0.f, 0.f, 0.f};

#pragma unroll
    for (int ks = 0; ks < 8; ++ks) {
#pragma unroll
      for (int ni = 0; ni < 4; ++ni) {
        short8 bv = *(const short8*)&yT[ni * 16 + r16][ks * 32 + kg * 8];
        acc[0][ni] = __builtin_amdgcn_mfma_f32_16x16x32_bf16(aw[0][ks], bv, acc[0][ni], 0, 0, 0);
        acc[1][ni] = __builtin_amdgcn_mfma_f32_16x16x32_bf16(aw[1][ks], bv, acc[1][ni], 0, 0, 0);
      }
    }

    // stats + sT write. D layout: px = ni*16 + r16 (col), d = mi*16 + kg*4 + j
#pragma unroll
    for (int mi = 0; mi < 2; ++mi)
#pragma unroll
      for (int ni = 0; ni < 4; ++ni) {
        const int px = p0 + ni * 16 + r16;
        ushort4 pk;
#pragma unroll
        for (int j = 0; j < 4; ++j) {
          float v = acc[mi][ni][j];
          ssum[mi * 4 + j] += v;
          ssq[mi * 4 + j] += v * v;
          ((unsigned short*)&pk)[j] = f2bf(v);
        }
        *(ushort4*)&sT[((size_t)b * NPX + px) * 32 + mi * 16 + kg * 4] = pk;
      }
    __syncthreads();
  }

  // reduce over the 16 lanes (r16) of each kg-group
#pragma unroll
  for (int i = 0; i < 8; ++i) {
    float sm = ssum[i], sq = ssq[i];
#pragma unroll
    for (int m = 8; m >= 1; m >>= 1) {
      sm += __shfl_xor(sm, m);
      sq += __shfl_xor(sq, m);
    }
    if (r16 == 0) {
      const int d = (i >> 2) * 16 + kg * 4 + (i & 3);
      red[w * 64 + d] = sm;
      red[w * 64 + 32 + d] = sq;
    }
  }
  __syncthreads();
  if (t < 64) {
    float tot = red[t] + red[64 + t] + red[128 + t] + red[192 + t];
    partials[(size_t)blockIdx.x * 64 + t] = tot;
  }
}

// ---------------- Kernel R: partials -> mu, rs --------------------------------
__global__ void kR(const float* __restrict__ partials, float* __restrict__ mu_rs) {
  const int b = blockIdx.x, d = threadIdx.x;  // 8 blocks x 32 threads
  float sm = 0.f, sq = 0.f;
  for (int ch = 0; ch < 64; ++ch) {
    const float* pp = &partials[(size_t)(b * 64 + ch) * 64];
    sm += pp[d];
    sq += pp[32 + d];
  }
  float m = sm * (1.f / 16384.f);
  float v = sq * (1.f / 16384.f) - m * m;
  mu_rs[b * 64 + d] = m;
  mu_rs[b * 64 + 32 + d] = rsqrtf(v + 1e-5f);
}

// ---------------- Kernel O: out = w_ex . relu((s-mu)*rs) + b_ex (MFMA) ------
// grid 2048 (b = blk>>8, tile = blk&255 -> 64 px), block 256; wave w -> 64 c
__global__ __launch_bounds__(256, 3)
void kO(const unsigned short* __restrict__ sT, const float* __restrict__ mu_rs,
        const float* __restrict__ w_ex, const float* __restrict__ b_ex,
        float* __restrict__ out) {
  const int t = threadIdx.x;
  const int w = t >> 6, lane = t & 63;
  const int r16 = lane & 15, kg = lane >> 4;
  const int b = blockIdx.x >> 8;
  const int p0 = (blockIdx.x & 255) * 64;
  const int c0 = w * 64;

  // A-frags: w_ex (fp32 [256][32]) -> bf16; 4 M-tiles per wave, K=32 (one MFMA)
  short8 aw[4];
  float bex[4];
#pragma unroll
  for (int mt = 0; mt < 4; ++mt) {
    const int c = c0 + mt * 16 + r16;
    const float* p = &w_ex[c * 32 + kg * 8];
    float4 f0 = *(const float4*)p;
    float4 f1 = *(const float4*)(p + 4);
    short8 a;
    a[0] = f2bf(f0.x); a[1] = f2bf(f0.y); a[2] = f2bf(f0.z); a[3] = f2bf(f0.w);
    a[4] = f2bf(f1.x); a[5] = f2bf(f1.y); a[6] = f2bf(f1.z); a[7] = f2bf(f1.w);
    aw[mt] = a;
    bex[mt] = b_ex[c0 + mt * 16 + kg * 4];  // placeholder, fixed below per-row
  }

  // per-lane mu/rs for its 8 k-channels (d = kg*8 .. +7)
  float m8[8], r8[8];
  {
    const float* mp = &mu_rs[b * 64 + kg * 8];
    const float* rp = &mu_rs[b * 64 + 32 + kg * 8];
#pragma unroll
    for (int q = 0; q < 8; ++q) { m8[q] = mp[q]; r8[q] = rp[q]; }
  }

  f32x4 acc[4][4];
#pragma unroll
  for (int mt = 0; mt < 4; ++mt)
#pragma unroll
    for (int ni = 0; ni < 4; ++ni) acc[mt][ni] = (f32x4){0.f, 0.f, 0.f, 0.f};

#pragma unroll
  for (int ni = 0; ni < 4; ++ni) {
    const int px = p0 + ni * 16 + r16;
    short8 sv = *(const short8*)&sT[((size_t)b * NPX + px) * 32 + kg * 8];
    short8 hb;
#pragma unroll
    for (int q = 0; q < 8; ++q) {
      float f = bf2f((unsigned short)sv[q]);
      float h = fmaxf((f - m8[q]) * r8[q], 0.f);
      hb[q] = f2bf(h);
    }
#pragma unroll
    for (int mt = 0; mt < 4; ++mt)
      acc[mt][ni] = __builtin_amdgcn_mfma_f32_16x16x32_bf16(aw[mt], hb, acc[mt][ni], 0, 0, 0);
  }

  float* __restrict__ ob = out + (size_t)b * 256 * NPX;
#pragma unroll
  for (int mt = 0; mt < 4; ++mt) {
#pragma unroll
    for (int j = 0; j < 4; ++j) {
      const int c = c0 + mt * 16 + kg * 4 + j;
      const float bv = b_ex[c];
#pragma unroll
      for (int ni = 0; ni < 4; ++ni) {
        const int px = p0 + ni * 16 + r16;
        ob[(size_t)c * NPX + px] = acc[mt][ni][j] + bv;
      }
    }
  }
}

extern "C" void kernel_launch(void* const* d_in, const int* in_sizes, int n_in,
                              void* d_out, int out_size, void* d_ws, size_t ws_size,
                              hipStream_t stream) {
  (void)in_sizes; (void)n_in; (void)out_size; (void)ws_size;
  const float* x    = (const float*)d_in[0];
  const float* wq   = (const float*)d_in[1];
  const float* bq   = (const float*)d_in[2];
  const float* wk   = (const float*)d_in[3];
  const float* bk   = (const float*)d_in[4];
  const float* w_sq = (const float*)d_in[5];
  // d_in[6] = b_sq: unused — per-channel bias before InstanceNorm cancels
  const float* w_ex = (const float*)d_in[7];
  const float* b_ex = (const float*)d_in[8];
  float* out = (float*)d_out;

  // ws layout: sT (bf16, 8*16384*32 = 16.78 MB) | partials (512*64 f32) | mu_rs
  unsigned short* sT = (unsigned short*)d_ws;
  float* partials = (float*)((char*)d_ws + (size_t)8 * NPX * 32 * 2);
  float* mu_rs = partials + (size_t)512 * 64;

  unsigned short* ybf = (unsigned short*)d_out;  // y staged in d_out (bf16)

  hipFuncSetAttribute((const void*)kA, hipFuncAttributeMaxDynamicSharedMemorySize,
                      LDS_A_BYTES);

  kA<<<2048, 512, LDS_A_BYTES, stream>>>(x, wq, bq, wk, bk, ybf);
  kS<<<512, 256, 0, stream>>>(ybf, w_sq, sT, partials);
  kR<<<8, 32, 0, stream>>>(partials, mu_rs);
  kO<<<2048, 256, 0, stream>>>(sT, mu_rs, w_ex, b_ex, out);
}